// Round 7
// baseline (76.920 us; speedup 1.0000x reference)
//
#include <hip/hip_runtime.h>

// Compress70, round 7.
// Same algorithm as round 6 (transposed channel-innermost inputs, 2x2-blocked
// ws1T, masked wave-uniform gathers, fused LDS un-transpose stores), but:
//  - h_index rows staged in LDS per block; ALL 18 patch offsets+masks computed
//    before ANY data load; 18 gathers issued as one cluster, pinned with
//    sched_barrier(0) so they can't be sunk to their uses (round-6 VGPR=52
//    showed the compiler serialized loads to save registers);
//  - half-size blocks, 3072-block grid = 12/CU = 3 exact resident rounds
//    (was 6/CU with 4 resident -> 25% tail loss).

#define N2 (2*128*128*128)   // 4194304
#define N1 (2*64*256*256)    // 8388608
#define WS_NEED ((size_t)(N2 + N1) * 4)

// ---------------- fused input transposes ----------------
__global__ __launch_bounds__(256) void prep_kernel(
    const float* __restrict__ lv1, const float* __restrict__ lv2,
    float* __restrict__ ws2T, float* __restrict__ ws1T)
{
    __shared__ float lds[8320];
    int bid  = blockIdx.x;
    int lane = threadIdx.x & 63;
    int wid  = threadIdx.x >> 6;
    if (bid < 512) {
        int b  = bid >> 8;
        int p0 = (bid & 255) << 6;
        const float* src = lv2 + (long)b * (128 * 16384);
#pragma unroll 4
        for (int it = 0; it < 32; ++it) {
            int c = it * 4 + wid;
            lds[c * 65 + lane] = src[c * 16384 + p0 + lane];
        }
        __syncthreads();
        float* dst = ws2T + (long)b * (16384 * 128) + (long)p0 * 128;
        int c  = threadIdx.x & 127;
        int pr = threadIdx.x >> 7;
#pragma unroll 4
        for (int it = 0; it < 32; ++it) {
            int p = it * 2 + pr;
            dst[p * 128 + c] = lds[c * 65 + p];
        }
    } else {
        int bb  = bid - 512;
        int sxc = bb & 3;
        int sy2 = (bb >> 2) & 127;
        int b   = bb >> 9;
        const float* src = lv1 + ((long)b << 22);
        int sy0 = sy2 * 2, sx0 = sxc * 64;
#pragma unroll 4
        for (int it = 0; it < 32; ++it) {
            int row = it * 4 + wid;
            int c = row >> 1, r = row & 1;
            lds[(r * 64 + lane) * 65 + c] =
                src[((long)c << 16) + ((sy0 + r) << 8) + sx0 + lane];
        }
        __syncthreads();
        float* dst = ws1T + ((long)b << 22) + ((long)sy2 << 15) + (sxc << 13);
#pragma unroll
        for (int it = 0; it < 8; ++it) {
            int g = it * 4 + wid;
            float4 v;
            v.x = lds[(2 * g) * 65 + lane];
            v.y = lds[(2 * g + 1) * 65 + lane];
            v.z = lds[(64 + 2 * g) * 65 + lane];
            v.w = lds[(64 + 2 * g + 1) * 65 + lane];
            *(float4*)(dst + (g << 8) + (lane << 2)) = v;
        }
    }
}

// ---------------- fused main gathers ----------------
__global__ __launch_bounds__(256) void mains_kernel(
    const float* __restrict__ ws2T, const float* __restrict__ ws1T,
    const int* __restrict__ hidx, float* __restrict__ out)
{
    __shared__ float lds[4160];     // main2: 32*129=4128; main1: 2*32*65=4160
    __shared__ int   sidx[102];     // main2: 3*34; main1: 3*18
    int bid  = blockIdx.x;
    int wid_all = (bid & 7) * 384 + (bid >> 3);   // bijective XCD-chunked
    int tid  = threadIdx.x;
    int lane = tid & 63;
    int wave = tid >> 6;

    if (wid_all < 1024) {
        // ---- main2: 32 consecutive pixels (one b,y row segment) ----
        int p0 = wid_all * 32;
        int b  = p0 >> 14;
        int y  = (p0 >> 7) & 127;
        int x0 = p0 & 127;
        const int*   hb  = hidx + (b << 14);
        const float* src = ws2T + ((long)b << 21);
        if (tid < 102) {                     // rows y-1..y+1, cols x0-1..x0+32
            int r = tid / 34, j = tid - r * 34;
            int a = y - 1 + r, e = x0 - 1 + j;
            int ok = ((unsigned)a < 128u) & ((unsigned)e < 128u);
            sidx[tid] = hb[ok ? ((a << 7) + e) : 0];
        }
        __syncthreads();
        int lane2 = lane << 1;
#pragma unroll
        for (int ii = 0; ii < 4; ++ii) {     // 4 pixel-pairs per wave
            int XlA = (wave << 3) + (ii << 1);
            int xA  = x0 + XlA;
            int   offA[9], offB[9];
            float mA[9], mB[9];
#pragma unroll
            for (int da = -1; da <= 1; ++da) {
#pragma unroll
                for (int de = -1; de <= 1; ++de) {
                    int k = (da + 1) * 3 + (de + 1);
                    int a = y + da;
                    {
                        int e  = xA + de;
                        int vj = ((unsigned)a < 128u) & ((unsigned)e < 128u);
                        int p  = __builtin_amdgcn_readfirstlane(
                                     sidx[(da + 1) * 34 + XlA + de + 1]);
                        int sr = (p >> 7) - da, sc = (p & 127) - de;
                        int vs = ((unsigned)sr < 128u) & ((unsigned)sc < 128u);
                        mA[k]   = (vj & vs) ? (1.f / 9.f) : 0.f;
                        offA[k] = vs ? (((sr << 7) + sc) << 7) : 0;
                    }
                    {
                        int e  = xA + 1 + de;
                        int vj = ((unsigned)a < 128u) & ((unsigned)e < 128u);
                        int p  = __builtin_amdgcn_readfirstlane(
                                     sidx[(da + 1) * 34 + XlA + de + 2]);
                        int sr = (p >> 7) - da, sc = (p & 127) - de;
                        int vs = ((unsigned)sr < 128u) & ((unsigned)sc < 128u);
                        mB[k]   = (vj & vs) ? (1.f / 9.f) : 0.f;
                        offB[k] = vs ? (((sr << 7) + sc) << 7) : 0;
                    }
                }
            }
            float2 vA[9], vB[9];
#pragma unroll
            for (int k = 0; k < 9; ++k) {
                vA[k] = *(const float2*)(src + offA[k] + lane2);
                vB[k] = *(const float2*)(src + offB[k] + lane2);
            }
            __builtin_amdgcn_sched_barrier(0);   // keep all 18 loads in flight
            float axA = 0.f, ayA = 0.f, axB = 0.f, ayB = 0.f;
#pragma unroll
            for (int k = 0; k < 9; ++k) {
                axA += vA[k].x * mA[k]; ayA += vA[k].y * mA[k];
                axB += vB[k].x * mB[k]; ayB += vB[k].y * mB[k];
            }
            lds[XlA * 129 + lane2]           = axA;
            lds[XlA * 129 + lane2 + 1]       = ayA;
            lds[(XlA + 1) * 129 + lane2]     = axB;
            lds[(XlA + 1) * 129 + lane2 + 1] = ayB;
        }
        __syncthreads();
        int xl = tid & 31, cb = tid >> 5;
#pragma unroll
        for (int it = 0; it < 16; ++it) {
            int c = it * 8 + cb;
            out[((long)(b * 128 + c) << 14) + (y << 7) + x0 + xl] =
                lds[xl * 129 + c];
        }
    } else {
        // ---- main1: 16 consecutive 2x2 tiles (one b,uy row segment) ----
        int w1  = wid_all - 1024;
        int t0  = w1 * 16;
        int b   = t0 >> 14;
        int uy  = (t0 >> 7) & 127;
        int ux0 = t0 & 127;
        const int*   hb  = hidx + (b << 14);
        const float* src = ws1T + ((long)b << 22);
        float* out1 = out + N2;
        if (tid < 54) {                      // rows uy-1..uy+1, cols ux0-1..ux0+16
            int r = tid / 18, j = tid - r * 18;
            int jy = uy - 1 + r, jx = ux0 - 1 + j;
            int ok = ((unsigned)jy < 128u) & ((unsigned)jx < 128u);
            sidx[tid] = hb[ok ? ((jy << 7) + jx) : 0];
        }
        __syncthreads();
        int lane4 = lane << 2;
#pragma unroll
        for (int ii = 0; ii < 2; ++ii) {     // 2 tile-pairs per wave
            int tiA = (wave << 2) + (ii << 1);
            int uxA = ux0 + tiA;
            int   offA[9], offB[9];
            float mA[9], mB[9];
#pragma unroll
            for (int ka = 0; ka < 3; ++ka) {
#pragma unroll
                for (int kb = 0; kb < 3; ++kb) {
                    int k  = ka * 3 + kb;
                    int jy = uy + 1 - ka;
                    int vy = ((unsigned)jy < 128u);
                    {
                        int jx = uxA + 1 - kb;
                        int vj = vy & ((unsigned)jx < 128u);
                        int p  = __builtin_amdgcn_readfirstlane(
                                     sidx[(2 - ka) * 18 + tiA + 2 - kb]);
                        int ry = (p >> 7) + ka - 1, rx = (p & 127) + kb - 1;
                        int vs = ((unsigned)ry < 128u) & ((unsigned)rx < 128u);
                        mA[k]   = (vj & vs) ? (1.f / 9.f) : 0.f;
                        offA[k] = vs ? ((ry << 15) + (rx << 8)) : 0;
                    }
                    {
                        int jx = uxA + 2 - kb;
                        int vj = vy & ((unsigned)jx < 128u);
                        int p  = __builtin_amdgcn_readfirstlane(
                                     sidx[(2 - ka) * 18 + tiA + 3 - kb]);
                        int ry = (p >> 7) + ka - 1, rx = (p & 127) + kb - 1;
                        int vs = ((unsigned)ry < 128u) & ((unsigned)rx < 128u);
                        mB[k]   = (vj & vs) ? (1.f / 9.f) : 0.f;
                        offB[k] = vs ? ((ry << 15) + (rx << 8)) : 0;
                    }
                }
            }
            float4 vA[9], vB[9];
#pragma unroll
            for (int k = 0; k < 9; ++k) {
                vA[k] = *(const float4*)(src + offA[k] + lane4);
                vB[k] = *(const float4*)(src + offB[k] + lane4);
            }
            __builtin_amdgcn_sched_barrier(0);   // keep all 18 loads in flight
            float4 aA = make_float4(0.f, 0.f, 0.f, 0.f);
            float4 aB = make_float4(0.f, 0.f, 0.f, 0.f);
#pragma unroll
            for (int k = 0; k < 9; ++k) {
                aA.x += vA[k].x * mA[k]; aA.y += vA[k].y * mA[k];
                aA.z += vA[k].z * mA[k]; aA.w += vA[k].w * mA[k];
                aB.x += vB[k].x * mB[k]; aB.y += vB[k].y * mB[k];
                aB.z += vB[k].z * mB[k]; aB.w += vB[k].w * mB[k];
            }
            int XA = tiA * 2;                // lds layout [r][X<32][c pad65]
            lds[(XA) * 65 + lane]            = aA.x;
            lds[(XA + 1) * 65 + lane]        = aA.y;
            lds[(32 + XA) * 65 + lane]       = aA.z;
            lds[(32 + XA + 1) * 65 + lane]   = aA.w;
            lds[(XA + 2) * 65 + lane]        = aB.x;
            lds[(XA + 3) * 65 + lane]        = aB.y;
            lds[(32 + XA + 2) * 65 + lane]   = aB.z;
            lds[(32 + XA + 3) * 65 + lane]   = aB.w;
        }
        __syncthreads();
        int Y0 = uy * 2, X0 = ux0 * 2;
        float* dst = out1 + ((long)b << 22);
        int xl = tid & 31, rsel = tid >> 5;
#pragma unroll
        for (int it = 0; it < 16; ++it) {
            int row = it * 8 + rsel;         // (c, r)
            int c = row >> 1, r = row & 1;
            dst[((long)c << 16) + ((Y0 + r) << 8) + X0 + xl] =
                lds[(r * 32 + xl) * 65 + c];
        }
    }
}

// ---------------- round-1 scalar fallback ----------------
__global__ __launch_bounds__(256) void fb2_kernel(
    const float* __restrict__ lv2, const int* __restrict__ hidx,
    float* __restrict__ out)
{
    int t = blockIdx.x * 256 + threadIdx.x;
    int x  = t & 127;
    int y  = (t >> 7) & 127;
    int bc = t >> 14;
    int b  = t >> 21;
    const int*   hb  = hidx + (b << 14);
    const float* src = lv2 + ((long)bc << 14);
    float acc = 0.f;
#pragma unroll
    for (int da = -1; da <= 1; ++da) {
        int a = y + da;
        if ((unsigned)a >= 128u) continue;
#pragma unroll
        for (int de = -1; de <= 1; ++de) {
            int e = x + de;
            if ((unsigned)e >= 128u) continue;
            int p  = hb[(a << 7) + e];
            int sr = (p >> 7) - da;
            int sc = (p & 127) - de;
            if ((unsigned)sr < 128u && (unsigned)sc < 128u)
                acc += src[(sr << 7) + sc];
        }
    }
    out[t] = acc * (1.f / 9.f);
}

__global__ __launch_bounds__(256) void fb1_kernel(
    const float* __restrict__ lv1, const int* __restrict__ hidx,
    float* __restrict__ out)
{
    int t = blockIdx.x * 256 + threadIdx.x;
    int X  = t & 255;
    int Y  = (t >> 8) & 255;
    int bc = t >> 16;
    int b  = t >> 22;
    const int*   hb  = hidx + (b << 14);
    const float* src = lv1 + ((long)bc << 16);
    int jyh = (Y + 2) >> 1;
    int jxh = (X + 2) >> 1;
    float acc = 0.f;
#pragma unroll
    for (int ka = 0; ka < 3; ++ka) {
        int jy = jyh - ka;
        if ((unsigned)jy >= 128u) continue;
        int dy = Y - 2 * jy;
#pragma unroll
        for (int kb = 0; kb < 3; ++kb) {
            int jx = jxh - kb;
            if ((unsigned)jx >= 128u) continue;
            int dx = X - 2 * jx;
            int p  = hb[(jy << 7) + jx];
            int sr = 2 * (p >> 7) + dy;
            int sc = 2 * (p & 127) + dx;
            if ((unsigned)sr < 256u && (unsigned)sc < 256u)
                acc += src[(sr << 8) + sc];
        }
    }
    out[t] = acc * (1.f / 9.f);
}

extern "C" void kernel_launch(void* const* d_in, const int* in_sizes, int n_in,
                              void* d_out, int out_size, void* d_ws, size_t ws_size,
                              hipStream_t stream)
{
    const float* lv1  = (const float*)d_in[0];
    const float* lv2  = (const float*)d_in[1];
    const int*   hidx = (const int*)d_in[2];
    float* out = (float*)d_out;

    if (ws_size >= WS_NEED) {
        float* ws2T = (float*)d_ws;
        float* ws1T = ws2T + N2;
        prep_kernel<<<1536, 256, 0, stream>>>(lv1, lv2, ws2T, ws1T);
        mains_kernel<<<3072, 256, 0, stream>>>(ws2T, ws1T, hidx, out);
    } else {
        fb2_kernel<<<N2 / 256, 256, 0, stream>>>(lv2, hidx, out);
        fb1_kernel<<<N1 / 256, 256, 0, stream>>>(lv1, hidx, out + N2);
    }
}